// Round 7
// baseline (272.313 us; speedup 1.0000x reference)
//
#include <hip/hip_runtime.h>

#define DIN 128
#define DH 64
#define DOUT 32
#define BN_EPS 1e-5f

#define BK 128          // nodes per bucket
#define BKSH 7          // log2(BK)
#define NBK_MAX 784     // ceil(100000/128)=782, padded
#define G 256           // counting-sort partition blocks
#define CAP 2560        // fixed per-bucket region capacity (mean 2048, +11 sigma)
#define CCAP 3584       // col region capacity: CAP + 128 nodes * 8 max pad (STRICT pad: 1..8 sentinels)

typedef __attribute__((ext_vector_type(8))) short short8;
typedef __attribute__((ext_vector_type(4))) float floatx4;

// bf16 helpers (RNE store, exact load)
__device__ __forceinline__ unsigned short f2bf(float f) {
    union { float f; unsigned u; } v; v.f = f;
    unsigned r = (v.u + 0x7FFFu + ((v.u >> 16) & 1u)) >> 16;
    return (unsigned short)r;
}
__device__ __forceinline__ float bf2f(unsigned short h) {
    union { unsigned u; float f; } v; v.u = ((unsigned)h) << 16;
    return v.f;
}
__device__ __forceinline__ float lo_f(unsigned u) {
    union { unsigned u; float f; } v; v.u = u << 16;
    return v.f;
}
__device__ __forceinline__ float hi_f(unsigned u) {
    union { unsigned u; float f; } v; v.u = u & 0xFFFF0000u;
    return v.f;
}
__device__ __forceinline__ unsigned pack2bf(float lo, float hi) {
    return (unsigned)f2bf(lo) | ((unsigned)f2bf(hi) << 16);
}

// ---------------- counting sort pass 1: per-block bucket histogram (g-major write) ----------------

__global__ __launch_bounds__(512) void hist_k(const int* __restrict__ dst, int* __restrict__ hist_g,
                                              int E, int nbk, int chunk) {
    __shared__ int hist[NBK_MAX];
    int g = blockIdx.x, tid = threadIdx.x;
    for (int b = tid; b < nbk; b += 512) hist[b] = 0;
    __syncthreads();
    int i0 = g * chunk, iend = min(i0 + chunk, E);
    for (int i = i0 + tid; i < iend; i += 512)
        atomicAdd(&hist[dst[i] >> BKSH], 1);
    __syncthreads();
    for (int b = tid; b < nbk; b += 512)
        hist_g[(size_t)g * nbk + b] = hist[b];   // coalesced row write
}

// ---------------- pass 2: per-bucket exclusive scan over the G=256 block-counts ----------------

__global__ __launch_bounds__(256) void scan_k(const int* __restrict__ hist_g, int* __restrict__ rowoff,
                                              int* __restrict__ tot, int nbk) {
    __shared__ int seg[16][17];
    int tid = threadIdx.x;
    int gl = tid >> 4, bl = tid & 15;
    int b = blockIdx.x * 16 + bl;
    bool bok = b < nbk;
    int vals[16];
    int psum = 0;
    #pragma unroll
    for (int j = 0; j < 16; j++) {
        int g = gl * 16 + j;
        int v = bok ? hist_g[(size_t)g * nbk + b] : 0;   // 16 independent loads in flight
        vals[j] = v; psum += v;
    }
    seg[gl][bl] = psum;
    __syncthreads();
    #pragma unroll
    for (int off = 1; off < 16; off <<= 1) {
        int t = (gl >= off) ? seg[gl - off][bl] : 0;
        __syncthreads();
        seg[gl][bl] += t;
        __syncthreads();
    }
    int run = seg[gl][bl] - psum;                        // exclusive base of this 16-g segment
    if (gl == 15 && bok) tot[b] = seg[15][bl];
    #pragma unroll
    for (int j = 0; j < 16; j++) {
        int g = gl * 16 + j;
        if (bok) rowoff[(size_t)g * nbk + b] = run;      // g-major: scatter_k reads rows coalesced
        run += vals[j];
    }
}

// ---------------- pass 3: scatter records into fixed-CAP bucket regions (no global atomics) ----------------

__global__ __launch_bounds__(512) void scatter_k(const int* __restrict__ src, const int* __restrict__ dst,
                                                 const int* __restrict__ rowoff,
                                                 unsigned* __restrict__ recs, int E, int nbk, int chunk) {
    __shared__ int cur[NBK_MAX];
    int g = blockIdx.x, tid = threadIdx.x;
    for (int b = tid; b < nbk; b += 512)
        cur[b] = b * CAP + rowoff[(size_t)g * nbk + b];   // coalesced row read (g-major)
    __syncthreads();
    int i0 = g * chunk, iend = min(i0 + chunk, E);
    for (int i = i0 + tid; i < iend; i += 512) {
        int s = src[i], d = dst[i];
        int b = d >> BKSH;
        int slot = atomicAdd(&cur[b], 1);   // LDS atomic
        if (slot < (b + 1) * CAP)           // overflow guard (never fires at CAP=mean+11sigma)
            recs[slot] = ((unsigned)s << BKSH) | (unsigned)(d & (BK - 1));
    }
}

// ---------------- pass 4: within-bucket node sort -> CSR, wave-private cursors ----------------
// STRICT padding: every node's list padded with sentinel n (zero feature row) to the NEXT
// multiple of 8 (1..8 sentinels, deg-0 -> 8). Guarantees col[e + pdeg-1] is ALWAYS a sentinel,
// so agg loops clamp-read without any cndmask value guard; overrun iterations add exact zeros.

__global__ __launch_bounds__(512) void csr_k(const unsigned* __restrict__ recs, const int* __restrict__ tot,
                                             float* __restrict__ dis, int2* __restrict__ rpde,
                                             int* __restrict__ col, int n) {
    __shared__ int deg8[8][BK];   // 4 KB
    __shared__ int wb[8][BK];     // 4 KB
    __shared__ int deg[BK], sc[BK], bas[BK];
    int b = blockIdx.x, tid = threadIdx.x;
    int w = tid >> 6, lane = tid & 63;
    for (int i = tid; i < 8 * BK; i += 512) ((int*)deg8)[i] = 0;
    __syncthreads();
    int lo = b * CAP;            // recs region (stride CAP)
    int clo = b * CCAP;          // col region (stride CCAP, has room for padding)
    int ne = min(tot[b], CAP);
    int hi = lo + ne;
    for (int e = lo + w * 64 + lane; e < hi; e += 512)
        atomicAdd(&deg8[w][recs[e] & (BK - 1)], 1);
    __syncthreads();
    if (tid < BK) {
        int run = 0;
        #pragma unroll
        for (int ww = 0; ww < 8; ww++) { wb[ww][tid] = run; run += deg8[ww][tid]; }
        deg[tid] = run;
        sc[tid] = (run + 8) & ~7;                 // STRICT pad: next multiple of 8 (>= deg+1)
    }
    __syncthreads();
    for (int off = 1; off < BK; off <<= 1) {
        int t = (tid < BK && tid >= off) ? sc[tid - off] : 0;
        __syncthreads();
        if (tid < BK) sc[tid] += t;
        __syncthreads();
    }
    if (tid < BK) {
        int d = deg[tid];
        int pdeg = (d + 8) & ~7;                  // STRICT pad
        int base = sc[tid] - pdeg;
        bas[tid] = base;
        int g = b * BK + tid;
        if (g < n) {
            dis[g] = rsqrtf((float)(d + 1));      // +1 self-loop
            rpde[g] = make_int2(clo + base, d);
        }
        for (int j = d; j < pdeg; j++)            // sentinel padding (1..8 per node)
            col[clo + base + j] = n;
    }
    __syncthreads();
    for (int i = tid; i < 8 * BK; i += 512)
        ((int*)wb)[i] += bas[i & (BK - 1)];       // wb[w][dl] += bas[dl]
    __syncthreads();
    for (int e = lo + w * 64 + lane; e < hi; e += 512) {
        unsigned r = recs[e];
        int dl = r & (BK - 1);
        int k = atomicAdd(&wb[w][dl], 1);         // wave-private cursor
        col[clo + k] = (int)(r >> BKSH);
    }
}

// ---------------- GEMM1 (MFMA bf16): h1 in QUARTER-SLICED layout [q][N+1][16] ----------------

__global__ __launch_bounds__(256) void gemm1_k(const float* __restrict__ x,
                                               const float* __restrict__ W1,
                                               const float* __restrict__ dis,
                                               unsigned short* __restrict__ h1s, int n, int np1) {
    __shared__ unsigned short xb[64][136];   // +8 pad: rows 272B apart -> 2-way bank alias (free)
    __shared__ unsigned short wt[64][136];
    int tid = threadIdx.x;
    int r0b = blockIdx.x * 64;

    for (int c = tid; c < 2048; c += 256) {
        int k = c >> 4, n4 = (c & 15) * 4;
        float4 v = ((const float4*)W1)[c];
        wt[n4 + 0][k] = f2bf(v.x);
        wt[n4 + 1][k] = f2bf(v.y);
        wt[n4 + 2][k] = f2bf(v.z);
        wt[n4 + 3][k] = f2bf(v.w);
    }
    for (int c = tid; c < 2048; c += 256) {
        int r = c >> 5, k4 = (c & 31) * 4;
        int gr = r0b + r;
        float4 v = make_float4(0.f, 0.f, 0.f, 0.f);
        if (gr < n) v = ((const float4*)x)[(gr << 5) + (k4 >> 2)];
        ushort4 o;
        o.x = f2bf(v.x); o.y = f2bf(v.y); o.z = f2bf(v.z); o.w = f2bf(v.w);
        *(ushort4*)&xb[r][k4] = o;
    }
    __syncthreads();

    int w = tid >> 6, lane = tid & 63;
    int rr = lane & 15, q = lane >> 4;
    floatx4 acc0 = {0.f, 0.f, 0.f, 0.f}, acc1 = acc0, acc2 = acc0, acc3 = acc0;
    #pragma unroll
    for (int kt = 0; kt < 4; kt++) {
        int k0 = kt * 32 + q * 8;
        short8 a  = *(const short8*)&xb[w * 16 + rr][k0];
        short8 b0 = *(const short8*)&wt[rr][k0];
        short8 b1 = *(const short8*)&wt[16 + rr][k0];
        short8 b2 = *(const short8*)&wt[32 + rr][k0];
        short8 b3 = *(const short8*)&wt[48 + rr][k0];
        acc0 = __builtin_amdgcn_mfma_f32_16x16x32_bf16(a, b0, acc0, 0, 0, 0);
        acc1 = __builtin_amdgcn_mfma_f32_16x16x32_bf16(a, b1, acc1, 0, 0, 0);
        acc2 = __builtin_amdgcn_mfma_f32_16x16x32_bf16(a, b2, acc2, 0, 0, 0);
        acc3 = __builtin_amdgcn_mfma_f32_16x16x32_bf16(a, b3, acc3, 0, 0, 0);
    }
    #pragma unroll
    for (int t = 0; t < 4; t++) {
        int gr = r0b + w * 16 + q * 4 + t;
        if (gr < n) {
            float dd = dis[gr];
            h1s[(size_t)0 * np1 * 16 + gr * 16 + rr] = f2bf(acc0[t] * dd);
            h1s[(size_t)1 * np1 * 16 + gr * 16 + rr] = f2bf(acc1[t] * dd);
            h1s[(size_t)2 * np1 * 16 + gr * 16 + rr] = f2bf(acc2[t] * dd);
            h1s[(size_t)3 * np1 * 16 + gr * 16 + rr] = f2bf(acc3[t] * dd);
        } else if (gr == n) {                    // sentinel zero row (all quarters)
            h1s[(size_t)0 * np1 * 16 + gr * 16 + rr] = 0;
            h1s[(size_t)1 * np1 * 16 + gr * 16 + rr] = 0;
            h1s[(size_t)2 * np1 * 16 + gr * 16 + rr] = 0;
            h1s[(size_t)3 * np1 * 16 + gr * 16 + rr] = 0;
        }
    }
}

// ---------------- Aggregation layer 1: XCD-sliced quarters, 16 nodes/wave, pipelined batches ----------------
// slot = blockIdx%8 ~ XCD: quarter q=slot>>1, node-half hn=slot&1 (quarter table 3.2MB L2-resident).
// lane = nodeslot(4b)|f(2b): lane owns 4 feats of one node. Inner loop is double-buffered:
// per half-iteration issue 8 gathers (batch A) + 8 col loads (batch B), sched_barrier(0),
// then consume A. Forces 8+ gathers in flight per lane (round-6 compiler serialized to ~1).
// Overrun iterations (itmax rounded to 16) clamp-read the STRICT sentinel pad -> add exact zeros.

__global__ __launch_bounds__(256) void agg1_k(const unsigned* __restrict__ h1p,
                                              const int2* __restrict__ rpde,
                                              const int* __restrict__ col,
                                              unsigned* __restrict__ outp, int n, int np1, int nh) {
    int b = blockIdx.x;
    int slot = b & 7;
    int q = slot >> 1, hn = slot & 1;
    int wv = threadIdx.x >> 6;
    int lane = threadIdx.x & 63;
    int ns = lane >> 2, f = lane & 3;
    int node = hn * nh + (b >> 3) * 64 + wv * 16 + ns;
    bool ok = node < n;
    int nd = ok ? node : n;

    int2 rd = rpde[ok ? node : 0];
    int e = rd.x;
    int dg = ok ? rd.y : 0;
    int pdg = (dg + 8) & ~7;                      // STRICT pad (matches csr_k)
    int pm = pdg - 1;

    int itmax = pdg;                              // wave max over the 16 nodes
    itmax = max(itmax, __shfl_xor(itmax, 4, 64));
    itmax = max(itmax, __shfl_xor(itmax, 8, 64));
    itmax = max(itmax, __shfl_xor(itmax, 16, 64));
    itmax = max(itmax, __shfl_xor(itmax, 32, 64));

    const uint2* qt = (const uint2*)h1p + (size_t)q * np1 * 4;   // quarter table, 4 uint2/row
    const int* cp = col + e;
    float s0 = 0.f, s1 = 0.f, s2 = 0.f, s3 = 0.f;

    // prologue: batch A = edges 0..7 (pm >= 7 always, no clamp needed)
    int a0 = cp[0], a1 = cp[1], a2 = cp[2], a3 = cp[3];
    int a4 = cp[4], a5 = cp[5], a6 = cp[6], a7 = cp[7];

    for (int i = 0; i < itmax; i += 16) {
        // issue 8 gathers (A) + 8 col loads (B, edges i+8..i+15)
        uint2 uA0 = qt[a0 * 4 + f], uA1 = qt[a1 * 4 + f];
        uint2 uA2 = qt[a2 * 4 + f], uA3 = qt[a3 * 4 + f];
        uint2 uA4 = qt[a4 * 4 + f], uA5 = qt[a5 * 4 + f];
        uint2 uA6 = qt[a6 * 4 + f], uA7 = qt[a7 * 4 + f];
        int i8 = i + 8;
        int b0 = cp[min(i8 + 0, pm)], b1 = cp[min(i8 + 1, pm)];
        int b2 = cp[min(i8 + 2, pm)], b3 = cp[min(i8 + 3, pm)];
        int b4 = cp[min(i8 + 4, pm)], b5 = cp[min(i8 + 5, pm)];
        int b6 = cp[min(i8 + 6, pm)], b7 = cp[min(i8 + 7, pm)];
        __builtin_amdgcn_sched_barrier(0);
        // consume A
        s0 += lo_f(uA0.x); s1 += hi_f(uA0.x); s2 += lo_f(uA0.y); s3 += hi_f(uA0.y);
        s0 += lo_f(uA1.x); s1 += hi_f(uA1.x); s2 += lo_f(uA1.y); s3 += hi_f(uA1.y);
        s0 += lo_f(uA2.x); s1 += hi_f(uA2.x); s2 += lo_f(uA2.y); s3 += hi_f(uA2.y);
        s0 += lo_f(uA3.x); s1 += hi_f(uA3.x); s2 += lo_f(uA3.y); s3 += hi_f(uA3.y);
        s0 += lo_f(uA4.x); s1 += hi_f(uA4.x); s2 += lo_f(uA4.y); s3 += hi_f(uA4.y);
        s0 += lo_f(uA5.x); s1 += hi_f(uA5.x); s2 += lo_f(uA5.y); s3 += hi_f(uA5.y);
        s0 += lo_f(uA6.x); s1 += hi_f(uA6.x); s2 += lo_f(uA6.y); s3 += hi_f(uA6.y);
        s0 += lo_f(uA7.x); s1 += hi_f(uA7.x); s2 += lo_f(uA7.y); s3 += hi_f(uA7.y);
        // issue 8 gathers (B) + 8 col loads (A', edges i+16..i+23, clamped)
        uint2 uB0 = qt[b0 * 4 + f], uB1 = qt[b1 * 4 + f];
        uint2 uB2 = qt[b2 * 4 + f], uB3 = qt[b3 * 4 + f];
        uint2 uB4 = qt[b4 * 4 + f], uB5 = qt[b5 * 4 + f];
        uint2 uB6 = qt[b6 * 4 + f], uB7 = qt[b7 * 4 + f];
        int i16 = i + 16;
        a0 = cp[min(i16 + 0, pm)]; a1 = cp[min(i16 + 1, pm)];
        a2 = cp[min(i16 + 2, pm)]; a3 = cp[min(i16 + 3, pm)];
        a4 = cp[min(i16 + 4, pm)]; a5 = cp[min(i16 + 5, pm)];
        a6 = cp[min(i16 + 6, pm)]; a7 = cp[min(i16 + 7, pm)];
        __builtin_amdgcn_sched_barrier(0);
        // consume B
        s0 += lo_f(uB0.x); s1 += hi_f(uB0.x); s2 += lo_f(uB0.y); s3 += hi_f(uB0.y);
        s0 += lo_f(uB1.x); s1 += hi_f(uB1.x); s2 += lo_f(uB1.y); s3 += hi_f(uB1.y);
        s0 += lo_f(uB2.x); s1 += hi_f(uB2.x); s2 += lo_f(uB2.y); s3 += hi_f(uB2.y);
        s0 += lo_f(uB3.x); s1 += hi_f(uB3.x); s2 += lo_f(uB3.y); s3 += hi_f(uB3.y);
        s0 += lo_f(uB4.x); s1 += hi_f(uB4.x); s2 += lo_f(uB4.y); s3 += hi_f(uB4.y);
        s0 += lo_f(uB5.x); s1 += hi_f(uB5.x); s2 += lo_f(uB5.y); s3 += hi_f(uB5.y);
        s0 += lo_f(uB6.x); s1 += hi_f(uB6.x); s2 += lo_f(uB6.y); s3 += hi_f(uB6.y);
        s0 += lo_f(uB7.x); s1 += hi_f(uB7.x); s2 += lo_f(uB7.y); s3 += hi_f(uB7.y);
    }

    uint2 us = qt[nd * 4 + f];                    // self row
    if (ok) {
        float dn = rsqrtf((float)(dg + 1));
        uint2 o;
        o.x = pack2bf((s0 + lo_f(us.x)) * dn, (s1 + hi_f(us.x)) * dn);
        o.y = pack2bf((s2 + lo_f(us.y)) * dn, (s3 + hi_f(us.y)) * dn);
        ((uint2*)outp)[((size_t)q * n + node) * 4 + f] = o;   // agg1b quarter layout [q][N][16]
    }
}

// ---------------- BN stats (bf16 input, quarter layout) ----------------

__global__ __launch_bounds__(256) void bnstats_k(const unsigned short* __restrict__ agg1b,
                                                 float* __restrict__ stats, int n) {
    int fidx = threadIdx.x & 63, g = threadIdx.x >> 6;
    int qq = fidx >> 4, fi = fidx & 15;
    const unsigned short* base = agg1b + (size_t)qq * n * 16 + fi;
    float sum = 0.f, sq = 0.f;
    for (int r = blockIdx.x * 4 + g; r < n; r += gridDim.x * 4) {
        float v = bf2f(base[(size_t)r * 16]);
        sum += v; sq += v * v;
    }
    __shared__ float s1[4][64], s2[4][64];
    s1[g][fidx] = sum; s2[g][fidx] = sq;
    __syncthreads();
    if (g == 0) {
        sum = s1[0][fidx] + s1[1][fidx] + s1[2][fidx] + s1[3][fidx];
        sq  = s2[0][fidx] + s2[1][fidx] + s2[2][fidx] + s2[3][fidx];
        atomicAdd(&stats[fidx], sum);
        atomicAdd(&stats[64 + fidx], sq);
    }
}

// ---------------- GEMM2 (MFMA bf16), BN fold inlined; h2 in HALF-SLICED layout [h][N+1][16] ----------------

__global__ __launch_bounds__(256) void gemm2_k(const unsigned short* __restrict__ agg1b,
                                               const float* __restrict__ W2,
                                               const float* __restrict__ stats,
                                               const float* __restrict__ gamma, const float* __restrict__ beta,
                                               const float* __restrict__ dis,
                                               unsigned short* __restrict__ h2s, float invn, int n, int np1) {
    __shared__ unsigned short ab[64][72];    // +8 pad
    __shared__ unsigned short wt[32][72];
    __shared__ float s_s[64], s_t[64];
    int tid = threadIdx.x;
    int r0b = blockIdx.x * 64;
    if (tid < 64) {                          // BN fold (b1 cancels by shift invariance)
        float mean = stats[tid] * invn;
        float var = stats[64 + tid] * invn - mean * mean;
        float s = gamma[tid] * rsqrtf(var + BN_EPS);
        s_s[tid] = s;
        s_t[tid] = beta[tid] - mean * s;
    }
    for (int c = tid; c < 512; c += 256) {   // stage W2^T (512 float4)
        int k = c >> 3, n4 = (c & 7) * 4;
        float4 v = ((const float4*)W2)[c];
        wt[n4 + 0][k] = f2bf(v.x);
        wt[n4 + 1][k] = f2bf(v.y);
        wt[n4 + 2][k] = f2bf(v.z);
        wt[n4 + 3][k] = f2bf(v.w);
    }
    __syncthreads();
    for (int c = tid; c < 512; c += 256) {
        int r = c >> 3, k0 = (c & 7) * 8;
        int gr = r0b + r;
        unsigned short tmp[8];
        if (gr < n) {
            const unsigned short* ap = &agg1b[(size_t)(k0 >> 4) * n * 16 + gr * 16 + (k0 & 8)];
            #pragma unroll
            for (int j = 0; j < 8; j++)
                tmp[j] = f2bf(fmaxf(bf2f(ap[j]) * s_s[k0 + j] + s_t[k0 + j], 0.f));
        } else {
            #pragma unroll
            for (int j = 0; j < 8; j++) tmp[j] = 0;
        }
        *(short8*)&ab[r][k0] = *(short8*)tmp;
    }
    __syncthreads();

    int w = tid >> 6, lane = tid & 63;
    int rr = lane & 15, q = lane >> 4;
    floatx4 acc0 = {0.f, 0.f, 0.f, 0.f}, acc1 = acc0;
    #pragma unroll
    for (int kt = 0; kt < 2; kt++) {
        int k0 = kt * 32 + q * 8;
        short8 a  = *(const short8*)&ab[w * 16 + rr][k0];
        short8 b0 = *(const short8*)&wt[rr][k0];
        short8 b1 = *(const short8*)&wt[16 + rr][k0];
        acc0 = __builtin_amdgcn_mfma_f32_16x16x32_bf16(a, b0, acc0, 0, 0, 0);
        acc1 = __builtin_amdgcn_mfma_f32_16x16x32_bf16(a, b1, acc1, 0, 0, 0);
    }
    #pragma unroll
    for (int t = 0; t < 4; t++) {
        int gr = r0b + w * 16 + q * 4 + t;
        if (gr < n) {
            float dd = dis[gr];
            h2s[(size_t)0 * np1 * 16 + gr * 16 + rr] = f2bf(acc0[t] * dd);
            h2s[(size_t)1 * np1 * 16 + gr * 16 + rr] = f2bf(acc1[t] * dd);
        } else if (gr == n) {                // sentinel zero row (both halves)
            h2s[(size_t)0 * np1 * 16 + gr * 16 + rr] = 0;
            h2s[(size_t)1 * np1 * 16 + gr * 16 + rr] = 0;
        }
    }
}

// ---------------- Aggregation layer 2: XCD-sliced halves, 16 nodes/wave, pipelined batches ----------------
// slot: h = slot>>2 (half-table, 3.2 MB, L2-resident), node-quarter qn = slot&3.

__global__ __launch_bounds__(256) void agg2_k(const unsigned* __restrict__ h2p,
                                              const int2* __restrict__ rpde,
                                              const int* __restrict__ col, const float* __restrict__ b2,
                                              float* __restrict__ out, int n, int np1, int nq) {
    int b = blockIdx.x;
    int slot = b & 7;
    int h = slot >> 2, qn = slot & 3;
    int wv = threadIdx.x >> 6;
    int lane = threadIdx.x & 63;
    int ns = lane >> 2, f = lane & 3;
    int node = qn * nq + (b >> 3) * 64 + wv * 16 + ns;
    bool ok = node < n;
    int nd = ok ? node : n;

    int2 rd = rpde[ok ? node : 0];
    int e = rd.x;
    int dg = ok ? rd.y : 0;
    int pdg = (dg + 8) & ~7;                      // STRICT pad (matches csr_k)
    int pm = pdg - 1;

    int itmax = pdg;
    itmax = max(itmax, __shfl_xor(itmax, 4, 64));
    itmax = max(itmax, __shfl_xor(itmax, 8, 64));
    itmax = max(itmax, __shfl_xor(itmax, 16, 64));
    itmax = max(itmax, __shfl_xor(itmax, 32, 64));

    const uint2* ht = (const uint2*)h2p + (size_t)h * np1 * 4;   // half table, 4 uint2/row
    const int* cp = col + e;
    float s0 = 0.f, s1 = 0.f, s2 = 0.f, s3 = 0.f;

    int a0 = cp[0], a1 = cp[1], a2 = cp[2], a3 = cp[3];
    int a4 = cp[4], a5 = cp[5], a6 = cp[6], a7 = cp[7];

    for (int i = 0; i < itmax; i += 16) {
        uint2 uA0 = ht[a0 * 4 + f], uA1 = ht[a1 * 4 + f];
        uint2 uA2 = ht[a2 * 4 + f], uA3 = ht[a3 * 4 + f];
        uint2 uA4 = ht[a4 * 4 + f], uA5 = ht[a5 * 4 + f];
        uint2 uA6 = ht[a6 * 4 + f], uA7 = ht[a7 * 4 + f];
        int i8 = i + 8;
        int b0 = cp[min(i8 + 0, pm)], b1 = cp[min(i8 + 1, pm)];
        int b2i = cp[min(i8 + 2, pm)], b3 = cp[min(i8 + 3, pm)];
        int b4 = cp[min(i8 + 4, pm)], b5 = cp[min(i8 + 5, pm)];
        int b6 = cp[min(i8 + 6, pm)], b7 = cp[min(i8 + 7, pm)];
        __builtin_amdgcn_sched_barrier(0);
        s0 += lo_f(uA0.x); s1 += hi_f(uA0.x); s2 += lo_f(uA0.y); s3 += hi_f(uA0.y);
        s0 += lo_f(uA1.x); s1 += hi_f(uA1.x); s2 += lo_f(uA1.y); s3 += hi_f(uA1.y);
        s0 += lo_f(uA2.x); s1 += hi_f(uA2.x); s2 += lo_f(uA2.y); s3 += hi_f(uA2.y);
        s0 += lo_f(uA3.x); s1 += hi_f(uA3.x); s2 += lo_f(uA3.y); s3 += hi_f(uA3.y);
        s0 += lo_f(uA4.x); s1 += hi_f(uA4.x); s2 += lo_f(uA4.y); s3 += hi_f(uA4.y);
        s0 += lo_f(uA5.x); s1 += hi_f(uA5.x); s2 += lo_f(uA5.y); s3 += hi_f(uA5.y);
        s0 += lo_f(uA6.x); s1 += hi_f(uA6.x); s2 += lo_f(uA6.y); s3 += hi_f(uA6.y);
        s0 += lo_f(uA7.x); s1 += hi_f(uA7.x); s2 += lo_f(uA7.y); s3 += hi_f(uA7.y);
        uint2 uB0 = ht[b0 * 4 + f], uB1 = ht[b1 * 4 + f];
        uint2 uB2 = ht[b2i * 4 + f], uB3 = ht[b3 * 4 + f];
        uint2 uB4 = ht[b4 * 4 + f], uB5 = ht[b5 * 4 + f];
        uint2 uB6 = ht[b6 * 4 + f], uB7 = ht[b7 * 4 + f];
        int i16 = i + 16;
        a0 = cp[min(i16 + 0, pm)]; a1 = cp[min(i16 + 1, pm)];
        a2 = cp[min(i16 + 2, pm)]; a3 = cp[min(i16 + 3, pm)];
        a4 = cp[min(i16 + 4, pm)]; a5 = cp[min(i16 + 5, pm)];
        a6 = cp[min(i16 + 6, pm)]; a7 = cp[min(i16 + 7, pm)];
        __builtin_amdgcn_sched_barrier(0);
        s0 += lo_f(uB0.x); s1 += hi_f(uB0.x); s2 += lo_f(uB0.y); s3 += hi_f(uB0.y);
        s0 += lo_f(uB1.x); s1 += hi_f(uB1.x); s2 += lo_f(uB1.y); s3 += hi_f(uB1.y);
        s0 += lo_f(uB2.x); s1 += hi_f(uB2.x); s2 += lo_f(uB2.y); s3 += hi_f(uB2.y);
        s0 += lo_f(uB3.x); s1 += hi_f(uB3.x); s2 += lo_f(uB3.y); s3 += hi_f(uB3.y);
        s0 += lo_f(uB4.x); s1 += hi_f(uB4.x); s2 += lo_f(uB4.y); s3 += hi_f(uB4.y);
        s0 += lo_f(uB5.x); s1 += hi_f(uB5.x); s2 += lo_f(uB5.y); s3 += hi_f(uB5.y);
        s0 += lo_f(uB6.x); s1 += hi_f(uB6.x); s2 += lo_f(uB6.y); s3 += hi_f(uB6.y);
        s0 += lo_f(uB7.x); s1 += hi_f(uB7.x); s2 += lo_f(uB7.y); s3 += hi_f(uB7.y);
    }

    uint2 us = ht[nd * 4 + f];
    if (ok) {
        float dn = rsqrtf((float)(dg + 1));
        float4 bb = ((const float4*)b2)[h * 4 + f];
        float4 o;
        o.x = (s0 + lo_f(us.x)) * dn + bb.x;
        o.y = (s1 + hi_f(us.x)) * dn + bb.y;
        o.z = (s2 + lo_f(us.y)) * dn + bb.z;
        o.w = (s3 + hi_f(us.y)) * dn + bb.w;
        ((float4*)out)[(size_t)node * 8 + h * 4 + f] = o;   // final output row-major [N][32]
    }
}

// ---------------- launch ----------------

extern "C" void kernel_launch(void* const* d_in, const int* in_sizes, int n_in,
                              void* d_out, int out_size, void* d_ws, size_t ws_size,
                              hipStream_t stream) {
    const float* x      = (const float*)d_in[0];
    const int*   ei     = (const int*)d_in[1];
    const float* W1     = (const float*)d_in[2];
    // d_in[3] = b1 (cancels inside BN)
    const float* gamma1 = (const float*)d_in[4];
    const float* beta1  = (const float*)d_in[5];
    const float* W2     = (const float*)d_in[6];
    const float* b2     = (const float*)d_in[7];
    float* out = (float*)d_out;

    int N = in_sizes[0] / DIN;
    int E = in_sizes[1] / 2;
    const int* src = ei;
    const int* dst = ei + E;
    int nbk = (N + BK - 1) >> BKSH;         // 782
    int chunk = (E + G - 1) / G;
    int np1 = N + 1;

    size_t off = 0;  // 4B units
    auto alloc = [&](size_t elems) -> void* {
        void* p = (char*)d_ws + off * 4;
        off += (elems + 127) & ~size_t(127);
        return p;
    };
    int*            hist_g = (int*)alloc((size_t)G * NBK_MAX);
    int*            rowoff = (int*)alloc((size_t)G * NBK_MAX);            // g-major [G][nbk]
    int*            tot    = (int*)alloc(NBK_MAX);
    unsigned*       recs   = (unsigned*)alloc((size_t)NBK_MAX * CAP);     // fixed-CAP regions
    int*            col    = (int*)alloc((size_t)NBK_MAX * CCAP);         // padded CSR cols (strict sentinel pad)
    float*          dis    = (float*)alloc(N);
    int2*           rpde   = (int2*)alloc((size_t)N * 2);
    float*          stats  = (float*)alloc(128);
    unsigned short* h1s    = (unsigned short*)alloc((size_t)np1 * DH / 2);  // bf16 quarter tables [4][N+1][16]
    unsigned short* agg1b  = (unsigned short*)alloc((size_t)N * DH / 2);    // bf16 quarter layout [4][N][16]
    unsigned short* h2s    = h1s;  // h1s dead after agg1_k; [2][N+1][16] fits inside region

    hipMemsetAsync(stats, 0, 128 * sizeof(float), stream);

    hist_k<<<G, 512, 0, stream>>>(dst, hist_g, E, nbk, chunk);
    scan_k<<<(nbk + 15) / 16, 256, 0, stream>>>(hist_g, rowoff, tot, nbk);
    scatter_k<<<G, 512, 0, stream>>>(src, dst, rowoff, recs, E, nbk, chunk);
    csr_k<<<nbk, 512, 0, stream>>>(recs, tot, dis, rpde, col, N);

    gemm1_k<<<(N + 63) / 64, 256, 0, stream>>>(x, W1, dis, h1s, N, np1);

    int nh = (N + 1) / 2;
    int agg1_blocks = 8 * ((nh + 63) / 64);
    agg1_k<<<agg1_blocks, 256, 0, stream>>>((const unsigned*)h1s, rpde, col, (unsigned*)agg1b,
                                            N, np1, nh);

    bnstats_k<<<400, 256, 0, stream>>>(agg1b, stats, N);

    gemm2_k<<<(N + 63) / 64, 256, 0, stream>>>(agg1b, W2, stats, gamma1, beta1, dis, h2s,
                                               1.0f / (float)N, N, np1);

    int nqn = (N + 3) / 4;
    int agg2_blocks = 8 * ((nqn + 63) / 64);
    agg2_k<<<agg2_blocks, 256, 0, stream>>>((const unsigned*)h2s, rpde, col, b2, out,
                                            N, np1, nqn);
}

// Round 8
// 262.943 us; speedup vs baseline: 1.0356x; 1.0356x over previous
//
#include <hip/hip_runtime.h>

#define DIN 128
#define DH 64
#define DOUT 32
#define BN_EPS 1e-5f

#define BK 128          // nodes per bucket
#define BKSH 7          // log2(BK)
#define NBK_MAX 784     // ceil(100000/128)=782, padded
#define G 256           // counting-sort partition blocks
#define CAP 2560        // fixed per-bucket region capacity (mean 2048, +11 sigma)
#define CCAP 3584       // col region capacity: CAP + 128 nodes * 8 max pad (STRICT pad: 1..8 sentinels)

typedef __attribute__((ext_vector_type(8))) short short8;
typedef __attribute__((ext_vector_type(4))) float floatx4;

// bf16 helpers (RNE store, exact load)
__device__ __forceinline__ unsigned short f2bf(float f) {
    union { float f; unsigned u; } v; v.f = f;
    unsigned r = (v.u + 0x7FFFu + ((v.u >> 16) & 1u)) >> 16;
    return (unsigned short)r;
}
__device__ __forceinline__ float bf2f(unsigned short h) {
    union { unsigned u; float f; } v; v.u = ((unsigned)h) << 16;
    return v.f;
}
__device__ __forceinline__ float lo_f(unsigned u) {
    union { unsigned u; float f; } v; v.u = u << 16;
    return v.f;
}
__device__ __forceinline__ float hi_f(unsigned u) {
    union { unsigned u; float f; } v; v.u = u & 0xFFFF0000u;
    return v.f;
}
__device__ __forceinline__ unsigned pack2bf(float lo, float hi) {
    return (unsigned)f2bf(lo) | ((unsigned)f2bf(hi) << 16);
}

// ---------------- counting sort pass 1: per-block bucket histogram (g-major write) ----------------

__global__ __launch_bounds__(512) void hist_k(const int* __restrict__ dst, int* __restrict__ hist_g,
                                              int E, int nbk, int chunk) {
    __shared__ int hist[NBK_MAX];
    int g = blockIdx.x, tid = threadIdx.x;
    for (int b = tid; b < nbk; b += 512) hist[b] = 0;
    __syncthreads();
    int i0 = g * chunk, iend = min(i0 + chunk, E);
    for (int i = i0 + tid; i < iend; i += 512)
        atomicAdd(&hist[dst[i] >> BKSH], 1);
    __syncthreads();
    for (int b = tid; b < nbk; b += 512)
        hist_g[(size_t)g * nbk + b] = hist[b];   // coalesced row write
}

// ---------------- pass 2: per-bucket exclusive scan over the G=256 block-counts ----------------

__global__ __launch_bounds__(256) void scan_k(const int* __restrict__ hist_g, int* __restrict__ rowoff,
                                              int* __restrict__ tot, int nbk) {
    __shared__ int seg[16][17];
    int tid = threadIdx.x;
    int gl = tid >> 4, bl = tid & 15;
    int b = blockIdx.x * 16 + bl;
    bool bok = b < nbk;
    int vals[16];
    int psum = 0;
    #pragma unroll
    for (int j = 0; j < 16; j++) {
        int g = gl * 16 + j;
        int v = bok ? hist_g[(size_t)g * nbk + b] : 0;   // 16 independent loads in flight
        vals[j] = v; psum += v;
    }
    seg[gl][bl] = psum;
    __syncthreads();
    #pragma unroll
    for (int off = 1; off < 16; off <<= 1) {
        int t = (gl >= off) ? seg[gl - off][bl] : 0;
        __syncthreads();
        seg[gl][bl] += t;
        __syncthreads();
    }
    int run = seg[gl][bl] - psum;                        // exclusive base of this 16-g segment
    if (gl == 15 && bok) tot[b] = seg[15][bl];
    #pragma unroll
    for (int j = 0; j < 16; j++) {
        int g = gl * 16 + j;
        if (bok) rowoff[(size_t)g * nbk + b] = run;      // g-major: scatter_k reads rows coalesced
        run += vals[j];
    }
}

// ---------------- pass 3: scatter records into fixed-CAP bucket regions (no global atomics) ----------------

__global__ __launch_bounds__(512) void scatter_k(const int* __restrict__ src, const int* __restrict__ dst,
                                                 const int* __restrict__ rowoff,
                                                 unsigned* __restrict__ recs, int E, int nbk, int chunk) {
    __shared__ int cur[NBK_MAX];
    int g = blockIdx.x, tid = threadIdx.x;
    for (int b = tid; b < nbk; b += 512)
        cur[b] = b * CAP + rowoff[(size_t)g * nbk + b];   // coalesced row read (g-major)
    __syncthreads();
    int i0 = g * chunk, iend = min(i0 + chunk, E);
    for (int i = i0 + tid; i < iend; i += 512) {
        int s = src[i], d = dst[i];
        int b = d >> BKSH;
        int slot = atomicAdd(&cur[b], 1);   // LDS atomic
        if (slot < (b + 1) * CAP)           // overflow guard (never fires at CAP=mean+11sigma)
            recs[slot] = ((unsigned)s << BKSH) | (unsigned)(d & (BK - 1));
    }
}

// ---------------- pass 4: within-bucket node sort -> CSR, wave-private cursors ----------------
// STRICT padding: every node's list padded with sentinel n (zero feature row) to the NEXT
// multiple of 8 (1..8 sentinels, deg-0 -> 8). Guarantees col[e + pdeg-1] is ALWAYS a sentinel,
// so agg loops clamp by VALUE only; overrun iterations add exact zeros.

__global__ __launch_bounds__(512) void csr_k(const unsigned* __restrict__ recs, const int* __restrict__ tot,
                                             float* __restrict__ dis, int2* __restrict__ rpde,
                                             int* __restrict__ col, int n) {
    __shared__ int deg8[8][BK];   // 4 KB
    __shared__ int wb[8][BK];     // 4 KB
    __shared__ int deg[BK], sc[BK], bas[BK];
    int b = blockIdx.x, tid = threadIdx.x;
    int w = tid >> 6, lane = tid & 63;
    for (int i = tid; i < 8 * BK; i += 512) ((int*)deg8)[i] = 0;
    __syncthreads();
    int lo = b * CAP;            // recs region (stride CAP)
    int clo = b * CCAP;          // col region (stride CCAP, has room for padding)
    int ne = min(tot[b], CAP);
    int hi = lo + ne;
    for (int e = lo + w * 64 + lane; e < hi; e += 512)
        atomicAdd(&deg8[w][recs[e] & (BK - 1)], 1);
    __syncthreads();
    if (tid < BK) {
        int run = 0;
        #pragma unroll
        for (int ww = 0; ww < 8; ww++) { wb[ww][tid] = run; run += deg8[ww][tid]; }
        deg[tid] = run;
        sc[tid] = (run + 8) & ~7;                 // STRICT pad: next multiple of 8 (>= deg+1)
    }
    __syncthreads();
    for (int off = 1; off < BK; off <<= 1) {
        int t = (tid < BK && tid >= off) ? sc[tid - off] : 0;
        __syncthreads();
        if (tid < BK) sc[tid] += t;
        __syncthreads();
    }
    if (tid < BK) {
        int d = deg[tid];
        int pdeg = (d + 8) & ~7;                  // STRICT pad
        int base = sc[tid] - pdeg;
        bas[tid] = base;
        int g = b * BK + tid;
        if (g < n) {
            dis[g] = rsqrtf((float)(d + 1));      // +1 self-loop
            rpde[g] = make_int2(clo + base, d);
        }
        for (int j = d; j < pdeg; j++)            // sentinel padding (1..8 per node)
            col[clo + base + j] = n;
    }
    __syncthreads();
    for (int i = tid; i < 8 * BK; i += 512)
        ((int*)wb)[i] += bas[i & (BK - 1)];       // wb[w][dl] += bas[dl]
    __syncthreads();
    for (int e = lo + w * 64 + lane; e < hi; e += 512) {
        unsigned r = recs[e];
        int dl = r & (BK - 1);
        int k = atomicAdd(&wb[w][dl], 1);         // wave-private cursor
        col[clo + k] = (int)(r >> BKSH);
    }
}

// ---------------- GEMM1 (MFMA bf16): h1 in QUARTER-SLICED layout [q][N+1][16] ----------------

__global__ __launch_bounds__(256) void gemm1_k(const float* __restrict__ x,
                                               const float* __restrict__ W1,
                                               const float* __restrict__ dis,
                                               unsigned short* __restrict__ h1s, int n, int np1) {
    __shared__ unsigned short xb[64][136];   // +8 pad: rows 272B apart -> 2-way bank alias (free)
    __shared__ unsigned short wt[64][136];
    int tid = threadIdx.x;
    int r0b = blockIdx.x * 64;

    for (int c = tid; c < 2048; c += 256) {
        int k = c >> 4, n4 = (c & 15) * 4;
        float4 v = ((const float4*)W1)[c];
        wt[n4 + 0][k] = f2bf(v.x);
        wt[n4 + 1][k] = f2bf(v.y);
        wt[n4 + 2][k] = f2bf(v.z);
        wt[n4 + 3][k] = f2bf(v.w);
    }
    for (int c = tid; c < 2048; c += 256) {
        int r = c >> 5, k4 = (c & 31) * 4;
        int gr = r0b + r;
        float4 v = make_float4(0.f, 0.f, 0.f, 0.f);
        if (gr < n) v = ((const float4*)x)[(gr << 5) + (k4 >> 2)];
        ushort4 o;
        o.x = f2bf(v.x); o.y = f2bf(v.y); o.z = f2bf(v.z); o.w = f2bf(v.w);
        *(ushort4*)&xb[r][k4] = o;
    }
    __syncthreads();

    int w = tid >> 6, lane = tid & 63;
    int rr = lane & 15, q = lane >> 4;
    floatx4 acc0 = {0.f, 0.f, 0.f, 0.f}, acc1 = acc0, acc2 = acc0, acc3 = acc0;
    #pragma unroll
    for (int kt = 0; kt < 4; kt++) {
        int k0 = kt * 32 + q * 8;
        short8 a  = *(const short8*)&xb[w * 16 + rr][k0];
        short8 b0 = *(const short8*)&wt[rr][k0];
        short8 b1 = *(const short8*)&wt[16 + rr][k0];
        short8 b2 = *(const short8*)&wt[32 + rr][k0];
        short8 b3 = *(const short8*)&wt[48 + rr][k0];
        acc0 = __builtin_amdgcn_mfma_f32_16x16x32_bf16(a, b0, acc0, 0, 0, 0);
        acc1 = __builtin_amdgcn_mfma_f32_16x16x32_bf16(a, b1, acc1, 0, 0, 0);
        acc2 = __builtin_amdgcn_mfma_f32_16x16x32_bf16(a, b2, acc2, 0, 0, 0);
        acc3 = __builtin_amdgcn_mfma_f32_16x16x32_bf16(a, b3, acc3, 0, 0, 0);
    }
    #pragma unroll
    for (int t = 0; t < 4; t++) {
        int gr = r0b + w * 16 + q * 4 + t;
        if (gr < n) {
            float dd = dis[gr];
            h1s[(size_t)0 * np1 * 16 + gr * 16 + rr] = f2bf(acc0[t] * dd);
            h1s[(size_t)1 * np1 * 16 + gr * 16 + rr] = f2bf(acc1[t] * dd);
            h1s[(size_t)2 * np1 * 16 + gr * 16 + rr] = f2bf(acc2[t] * dd);
            h1s[(size_t)3 * np1 * 16 + gr * 16 + rr] = f2bf(acc3[t] * dd);
        } else if (gr == n) {                    // sentinel zero row (all quarters)
            h1s[(size_t)0 * np1 * 16 + gr * 16 + rr] = 0;
            h1s[(size_t)1 * np1 * 16 + gr * 16 + rr] = 0;
            h1s[(size_t)2 * np1 * 16 + gr * 16 + rr] = 0;
            h1s[(size_t)3 * np1 * 16 + gr * 16 + rr] = 0;
        }
    }
}

// ---------------- Aggregation layer 1: XCD-sliced quarters, 16 nodes/wave, vectorized col + shfl ----------------
// slot = blockIdx%8 ~ XCD: quarter q=slot>>1, node-half hn=slot&1 (quarter table 3.2MB L2-resident).
// lane = nodeslot(4b)|f(2b). TA-lookup economy: per 8-edge batch, col is ONE int2 load per lane
// (16 transactions/instr, covers all 8 slots x 16 nodes) instead of 8 scalar instrs (128 lookups);
// the 8 indices reach the 4 f-lanes via __shfl (DS pipe, no TA cost). Value-clamp to sentinel n
// for slots > pm. Gathers for batch i and the col vector for batch i+8 are issued together ahead
// of a sched_barrier(0) so 9 VMEM ops stay in flight.

__global__ __launch_bounds__(256) void agg1_k(const unsigned* __restrict__ h1p,
                                              const int2* __restrict__ rpde,
                                              const int* __restrict__ col,
                                              unsigned* __restrict__ outp, int n, int np1, int nh) {
    int b = blockIdx.x;
    int slot = b & 7;
    int q = slot >> 1, hn = slot & 1;
    int wv = threadIdx.x >> 6;
    int lane = threadIdx.x & 63;
    int ns = lane >> 2, f = lane & 3;
    int node = hn * nh + (b >> 3) * 64 + wv * 16 + ns;
    bool ok = node < n;
    int nd = ok ? node : n;

    int2 rd = rpde[ok ? node : 0];
    int e = rd.x;
    int dg = ok ? rd.y : 0;
    int pdg = (dg + 8) & ~7;                      // STRICT pad (matches csr_k)
    int pm = pdg - 1;

    int itmax = pdg;                              // wave max over the 16 nodes
    itmax = max(itmax, __shfl_xor(itmax, 4, 64));
    itmax = max(itmax, __shfl_xor(itmax, 8, 64));
    itmax = max(itmax, __shfl_xor(itmax, 16, 64));
    itmax = max(itmax, __shfl_xor(itmax, 32, 64));

    const uint2* qt = (const uint2*)h1p + (size_t)q * np1 * 4;   // quarter table, 4 uint2/row
    const int* cp = col + e;                      // e is 8-int aligned (strict-pad scan)
    int bl = lane & 0x3C;                         // ns*4: base lane of this node's group
    float s0 = 0.f, s1 = 0.f, s2 = 0.f, s3 = 0.f;

    // prologue: col pair for edges 2f,2f+1 (pm >= 7 always, no clamp for batch 0)
    int2 cc = ((const int2*)cp)[f];
    int a0 = __shfl(cc.x, bl + 0, 64), a1 = __shfl(cc.y, bl + 0, 64);
    int a2 = __shfl(cc.x, bl + 1, 64), a3 = __shfl(cc.y, bl + 1, 64);
    int a4 = __shfl(cc.x, bl + 2, 64), a5 = __shfl(cc.y, bl + 2, 64);
    int a6 = __shfl(cc.x, bl + 3, 64), a7 = __shfl(cc.y, bl + 3, 64);

    for (int i = 0; i < itmax; i += 8) {
        // issue 8 gathers (batch i) + 1 col vector (batch i+8; may over-read, value-clamped)
        uint2 u0 = qt[a0 * 4 + f], u1 = qt[a1 * 4 + f];
        uint2 u2 = qt[a2 * 4 + f], u3 = qt[a3 * 4 + f];
        uint2 u4 = qt[a4 * 4 + f], u5 = qt[a5 * 4 + f];
        uint2 u6 = qt[a6 * 4 + f], u7 = qt[a7 * 4 + f];
        int2 cn = ((const int2*)(cp + i + 8))[f];
        __builtin_amdgcn_sched_barrier(0);
        // consume batch i
        s0 += lo_f(u0.x); s1 += hi_f(u0.x); s2 += lo_f(u0.y); s3 += hi_f(u0.y);
        s0 += lo_f(u1.x); s1 += hi_f(u1.x); s2 += lo_f(u1.y); s3 += hi_f(u1.y);
        s0 += lo_f(u2.x); s1 += hi_f(u2.x); s2 += lo_f(u2.y); s3 += hi_f(u2.y);
        s0 += lo_f(u3.x); s1 += hi_f(u3.x); s2 += lo_f(u3.y); s3 += hi_f(u3.y);
        s0 += lo_f(u4.x); s1 += hi_f(u4.x); s2 += lo_f(u4.y); s3 += hi_f(u4.y);
        s0 += lo_f(u5.x); s1 += hi_f(u5.x); s2 += lo_f(u5.y); s3 += hi_f(u5.y);
        s0 += lo_f(u6.x); s1 += hi_f(u6.x); s2 += lo_f(u6.y); s3 += hi_f(u6.y);
        s0 += lo_f(u7.x); s1 += hi_f(u7.x); s2 += lo_f(u7.y); s3 += hi_f(u7.y);
        // distribute next batch indices; clamp slots past pm to sentinel n (zero row)
        int i8 = i + 8;
        a0 = __shfl(cn.x, bl + 0, 64); a0 = (i8 + 0 <= pm) ? a0 : n;
        a1 = __shfl(cn.y, bl + 0, 64); a1 = (i8 + 1 <= pm) ? a1 : n;
        a2 = __shfl(cn.x, bl + 1, 64); a2 = (i8 + 2 <= pm) ? a2 : n;
        a3 = __shfl(cn.y, bl + 1, 64); a3 = (i8 + 3 <= pm) ? a3 : n;
        a4 = __shfl(cn.x, bl + 2, 64); a4 = (i8 + 4 <= pm) ? a4 : n;
        a5 = __shfl(cn.y, bl + 2, 64); a5 = (i8 + 5 <= pm) ? a5 : n;
        a6 = __shfl(cn.x, bl + 3, 64); a6 = (i8 + 6 <= pm) ? a6 : n;
        a7 = __shfl(cn.y, bl + 3, 64); a7 = (i8 + 7 <= pm) ? a7 : n;
    }

    uint2 us = qt[nd * 4 + f];                    // self row
    if (ok) {
        float dn = rsqrtf((float)(dg + 1));
        uint2 o;
        o.x = pack2bf((s0 + lo_f(us.x)) * dn, (s1 + hi_f(us.x)) * dn);
        o.y = pack2bf((s2 + lo_f(us.y)) * dn, (s3 + hi_f(us.y)) * dn);
        ((uint2*)outp)[((size_t)q * n + node) * 4 + f] = o;   // agg1b quarter layout [q][N][16]
    }
}

// ---------------- BN stats (bf16 input, quarter layout) ----------------

__global__ __launch_bounds__(256) void bnstats_k(const unsigned short* __restrict__ agg1b,
                                                 float* __restrict__ stats, int n) {
    int fidx = threadIdx.x & 63, g = threadIdx.x >> 6;
    int qq = fidx >> 4, fi = fidx & 15;
    const unsigned short* base = agg1b + (size_t)qq * n * 16 + fi;
    float sum = 0.f, sq = 0.f;
    for (int r = blockIdx.x * 4 + g; r < n; r += gridDim.x * 4) {
        float v = bf2f(base[(size_t)r * 16]);
        sum += v; sq += v * v;
    }
    __shared__ float s1[4][64], s2[4][64];
    s1[g][fidx] = sum; s2[g][fidx] = sq;
    __syncthreads();
    if (g == 0) {
        sum = s1[0][fidx] + s1[1][fidx] + s1[2][fidx] + s1[3][fidx];
        sq  = s2[0][fidx] + s2[1][fidx] + s2[2][fidx] + s2[3][fidx];
        atomicAdd(&stats[fidx], sum);
        atomicAdd(&stats[64 + fidx], sq);
    }
}

// ---------------- GEMM2 (MFMA bf16), BN fold inlined; h2 in HALF-SLICED layout [h][N+1][16] ----------------

__global__ __launch_bounds__(256) void gemm2_k(const unsigned short* __restrict__ agg1b,
                                               const float* __restrict__ W2,
                                               const float* __restrict__ stats,
                                               const float* __restrict__ gamma, const float* __restrict__ beta,
                                               const float* __restrict__ dis,
                                               unsigned short* __restrict__ h2s, float invn, int n, int np1) {
    __shared__ unsigned short ab[64][72];    // +8 pad
    __shared__ unsigned short wt[32][72];
    __shared__ float s_s[64], s_t[64];
    int tid = threadIdx.x;
    int r0b = blockIdx.x * 64;
    if (tid < 64) {                          // BN fold (b1 cancels by shift invariance)
        float mean = stats[tid] * invn;
        float var = stats[64 + tid] * invn - mean * mean;
        float s = gamma[tid] * rsqrtf(var + BN_EPS);
        s_s[tid] = s;
        s_t[tid] = beta[tid] - mean * s;
    }
    for (int c = tid; c < 512; c += 256) {   // stage W2^T (512 float4)
        int k = c >> 3, n4 = (c & 7) * 4;
        float4 v = ((const float4*)W2)[c];
        wt[n4 + 0][k] = f2bf(v.x);
        wt[n4 + 1][k] = f2bf(v.y);
        wt[n4 + 2][k] = f2bf(v.z);
        wt[n4 + 3][k] = f2bf(v.w);
    }
    __syncthreads();
    for (int c = tid; c < 512; c += 256) {
        int r = c >> 3, k0 = (c & 7) * 8;
        int gr = r0b + r;
        unsigned short tmp[8];
        if (gr < n) {
            const unsigned short* ap = &agg1b[(size_t)(k0 >> 4) * n * 16 + gr * 16 + (k0 & 8)];
            #pragma unroll
            for (int j = 0; j < 8; j++)
                tmp[j] = f2bf(fmaxf(bf2f(ap[j]) * s_s[k0 + j] + s_t[k0 + j], 0.f));
        } else {
            #pragma unroll
            for (int j = 0; j < 8; j++) tmp[j] = 0;
        }
        *(short8*)&ab[r][k0] = *(short8*)tmp;
    }
    __syncthreads();

    int w = tid >> 6, lane = tid & 63;
    int rr = lane & 15, q = lane >> 4;
    floatx4 acc0 = {0.f, 0.f, 0.f, 0.f}, acc1 = acc0;
    #pragma unroll
    for (int kt = 0; kt < 2; kt++) {
        int k0 = kt * 32 + q * 8;
        short8 a  = *(const short8*)&ab[w * 16 + rr][k0];
        short8 b0 = *(const short8*)&wt[rr][k0];
        short8 b1 = *(const short8*)&wt[16 + rr][k0];
        acc0 = __builtin_amdgcn_mfma_f32_16x16x32_bf16(a, b0, acc0, 0, 0, 0);
        acc1 = __builtin_amdgcn_mfma_f32_16x16x32_bf16(a, b1, acc1, 0, 0, 0);
    }
    #pragma unroll
    for (int t = 0; t < 4; t++) {
        int gr = r0b + w * 16 + q * 4 + t;
        if (gr < n) {
            float dd = dis[gr];
            h2s[(size_t)0 * np1 * 16 + gr * 16 + rr] = f2bf(acc0[t] * dd);
            h2s[(size_t)1 * np1 * 16 + gr * 16 + rr] = f2bf(acc1[t] * dd);
        } else if (gr == n) {                // sentinel zero row (both halves)
            h2s[(size_t)0 * np1 * 16 + gr * 16 + rr] = 0;
            h2s[(size_t)1 * np1 * 16 + gr * 16 + rr] = 0;
        }
    }
}

// ---------------- Aggregation layer 2: XCD-sliced halves, 16 nodes/wave, vectorized col + shfl ----------------
// slot: h = slot>>2 (half-table, 3.2 MB, L2-resident), node-quarter qn = slot&3.

__global__ __launch_bounds__(256) void agg2_k(const unsigned* __restrict__ h2p,
                                              const int2* __restrict__ rpde,
                                              const int* __restrict__ col, const float* __restrict__ b2,
                                              float* __restrict__ out, int n, int np1, int nq) {
    int b = blockIdx.x;
    int slot = b & 7;
    int h = slot >> 2, qn = slot & 3;
    int wv = threadIdx.x >> 6;
    int lane = threadIdx.x & 63;
    int ns = lane >> 2, f = lane & 3;
    int node = qn * nq + (b >> 3) * 64 + wv * 16 + ns;
    bool ok = node < n;
    int nd = ok ? node : n;

    int2 rd = rpde[ok ? node : 0];
    int e = rd.x;
    int dg = ok ? rd.y : 0;
    int pdg = (dg + 8) & ~7;                      // STRICT pad (matches csr_k)
    int pm = pdg - 1;

    int itmax = pdg;
    itmax = max(itmax, __shfl_xor(itmax, 4, 64));
    itmax = max(itmax, __shfl_xor(itmax, 8, 64));
    itmax = max(itmax, __shfl_xor(itmax, 16, 64));
    itmax = max(itmax, __shfl_xor(itmax, 32, 64));

    const uint2* ht = (const uint2*)h2p + (size_t)h * np1 * 4;   // half table, 4 uint2/row
    const int* cp = col + e;
    int bl = lane & 0x3C;
    float s0 = 0.f, s1 = 0.f, s2 = 0.f, s3 = 0.f;

    int2 cc = ((const int2*)cp)[f];
    int a0 = __shfl(cc.x, bl + 0, 64), a1 = __shfl(cc.y, bl + 0, 64);
    int a2 = __shfl(cc.x, bl + 1, 64), a3 = __shfl(cc.y, bl + 1, 64);
    int a4 = __shfl(cc.x, bl + 2, 64), a5 = __shfl(cc.y, bl + 2, 64);
    int a6 = __shfl(cc.x, bl + 3, 64), a7 = __shfl(cc.y, bl + 3, 64);

    for (int i = 0; i < itmax; i += 8) {
        uint2 u0 = ht[a0 * 4 + f], u1 = ht[a1 * 4 + f];
        uint2 u2 = ht[a2 * 4 + f], u3 = ht[a3 * 4 + f];
        uint2 u4 = ht[a4 * 4 + f], u5 = ht[a5 * 4 + f];
        uint2 u6 = ht[a6 * 4 + f], u7 = ht[a7 * 4 + f];
        int2 cn = ((const int2*)(cp + i + 8))[f];
        __builtin_amdgcn_sched_barrier(0);
        s0 += lo_f(u0.x); s1 += hi_f(u0.x); s2 += lo_f(u0.y); s3 += hi_f(u0.y);
        s0 += lo_f(u1.x); s1 += hi_f(u1.x); s2 += lo_f(u1.y); s3 += hi_f(u1.y);
        s0 += lo_f(u2.x); s1 += hi_f(u2.x); s2 += lo_f(u2.y); s3 += hi_f(u2.y);
        s0 += lo_f(u3.x); s1 += hi_f(u3.x); s2 += lo_f(u3.y); s3 += hi_f(u3.y);
        s0 += lo_f(u4.x); s1 += hi_f(u4.x); s2 += lo_f(u4.y); s3 += hi_f(u4.y);
        s0 += lo_f(u5.x); s1 += hi_f(u5.x); s2 += lo_f(u5.y); s3 += hi_f(u5.y);
        s0 += lo_f(u6.x); s1 += hi_f(u6.x); s2 += lo_f(u6.y); s3 += hi_f(u6.y);
        s0 += lo_f(u7.x); s1 += hi_f(u7.x); s2 += lo_f(u7.y); s3 += hi_f(u7.y);
        int i8 = i + 8;
        a0 = __shfl(cn.x, bl + 0, 64); a0 = (i8 + 0 <= pm) ? a0 : n;
        a1 = __shfl(cn.y, bl + 0, 64); a1 = (i8 + 1 <= pm) ? a1 : n;
        a2 = __shfl(cn.x, bl + 1, 64); a2 = (i8 + 2 <= pm) ? a2 : n;
        a3 = __shfl(cn.y, bl + 1, 64); a3 = (i8 + 3 <= pm) ? a3 : n;
        a4 = __shfl(cn.x, bl + 2, 64); a4 = (i8 + 4 <= pm) ? a4 : n;
        a5 = __shfl(cn.y, bl + 2, 64); a5 = (i8 + 5 <= pm) ? a5 : n;
        a6 = __shfl(cn.x, bl + 3, 64); a6 = (i8 + 6 <= pm) ? a6 : n;
        a7 = __shfl(cn.y, bl + 3, 64); a7 = (i8 + 7 <= pm) ? a7 : n;
    }

    uint2 us = ht[nd * 4 + f];
    if (ok) {
        float dn = rsqrtf((float)(dg + 1));
        float4 bb = ((const float4*)b2)[h * 4 + f];
        float4 o;
        o.x = (s0 + lo_f(us.x)) * dn + bb.x;
        o.y = (s1 + hi_f(us.x)) * dn + bb.y;
        o.z = (s2 + lo_f(us.y)) * dn + bb.z;
        o.w = (s3 + hi_f(us.y)) * dn + bb.w;
        ((float4*)out)[(size_t)node * 8 + h * 4 + f] = o;   // final output row-major [N][32]
    }
}

// ---------------- launch ----------------

extern "C" void kernel_launch(void* const* d_in, const int* in_sizes, int n_in,
                              void* d_out, int out_size, void* d_ws, size_t ws_size,
                              hipStream_t stream) {
    const float* x      = (const float*)d_in[0];
    const int*   ei     = (const int*)d_in[1];
    const float* W1     = (const float*)d_in[2];
    // d_in[3] = b1 (cancels inside BN)
    const float* gamma1 = (const float*)d_in[4];
    const float* beta1  = (const float*)d_in[5];
    const float* W2     = (const float*)d_in[6];
    const float* b2     = (const float*)d_in[7];
    float* out = (float*)d_out;

    int N = in_sizes[0] / DIN;
    int E = in_sizes[1] / 2;
    const int* src = ei;
    const int* dst = ei + E;
    int nbk = (N + BK - 1) >> BKSH;         // 782
    int chunk = (E + G - 1) / G;
    int np1 = N + 1;

    size_t off = 0;  // 4B units
    auto alloc = [&](size_t elems) -> void* {
        void* p = (char*)d_ws + off * 4;
        off += (elems + 127) & ~size_t(127);
        return p;
    };
    int*            hist_g = (int*)alloc((size_t)G * NBK_MAX);
    int*            rowoff = (int*)alloc((size_t)G * NBK_MAX);            // g-major [G][nbk]
    int*            tot    = (int*)alloc(NBK_MAX);
    unsigned*       recs   = (unsigned*)alloc((size_t)NBK_MAX * CAP);     // fixed-CAP regions
    int*            col    = (int*)alloc((size_t)NBK_MAX * CCAP);         // padded CSR cols (strict sentinel pad)
    float*          dis    = (float*)alloc(N);
    int2*           rpde   = (int2*)alloc((size_t)N * 2);
    float*          stats  = (float*)alloc(128);
    unsigned short* h1s    = (unsigned short*)alloc((size_t)np1 * DH / 2);  // bf16 quarter tables [4][N+1][16]
    unsigned short* agg1b  = (unsigned short*)alloc((size_t)N * DH / 2);    // bf16 quarter layout [4][N][16]
    unsigned short* h2s    = h1s;  // h1s dead after agg1_k; [2][N+1][16] fits inside region

    hipMemsetAsync(stats, 0, 128 * sizeof(float), stream);

    hist_k<<<G, 512, 0, stream>>>(dst, hist_g, E, nbk, chunk);
    scan_k<<<(nbk + 15) / 16, 256, 0, stream>>>(hist_g, rowoff, tot, nbk);
    scatter_k<<<G, 512, 0, stream>>>(src, dst, rowoff, recs, E, nbk, chunk);
    csr_k<<<nbk, 512, 0, stream>>>(recs, tot, dis, rpde, col, N);

    gemm1_k<<<(N + 63) / 64, 256, 0, stream>>>(x, W1, dis, h1s, N, np1);

    int nh = (N + 1) / 2;
    int agg1_blocks = 8 * ((nh + 63) / 64);
    agg1_k<<<agg1_blocks, 256, 0, stream>>>((const unsigned*)h1s, rpde, col, (unsigned*)agg1b,
                                            N, np1, nh);

    bnstats_k<<<400, 256, 0, stream>>>(agg1b, stats, N);

    gemm2_k<<<(N + 63) / 64, 256, 0, stream>>>(agg1b, W2, stats, gamma1, beta1, dis, h2s,
                                               1.0f / (float)N, N, np1);

    int nqn = (N + 3) / 4;
    int agg2_blocks = 8 * ((nqn + 63) / 64);
    agg2_k<<<agg2_blocks, 256, 0, stream>>>((const unsigned*)h2s, rpde, col, b2, out,
                                            N, np1, nqn);
}